// Round 13
// baseline (324.846 us; speedup 1.0000x reference)
//
#include <hip/hip_runtime.h>
#include <stdint.h>
#include <stddef.h>

#define NNODES 50000
#define NEDGES 500000
#define DIM 256
#define NHEAD 8
#define HDIM 32
#define MPAD 50048   /* 391 * 128 */
#define NEGS 0.2f
#define SCAN_BLOCKS 196    /* ceil(50000/256) */
#define COUNT_BLOCKS 1954  /* ceil(500000/256) */
#define CVT_BLOCKS 12500   /* 50000*256/1024 */
#define TR_BLOCKS 192      /* 8*8*3 */
#define GEMM_BLOCKS 782    /* 391*2 */

typedef __attribute__((ext_vector_type(8))) short bf16x8;
typedef __attribute__((ext_vector_type(4))) float f32x4;
typedef __attribute__((ext_vector_type(2))) float f32x2;
typedef __attribute__((ext_vector_type(4))) unsigned short u16x4;

__device__ __forceinline__ unsigned short f2bf(float f) {
    uint32_t u = __builtin_bit_cast(uint32_t, f);
    uint32_t r = (u + 0x7FFFu + ((u >> 16) & 1u)) >> 16;
    return (unsigned short)r;
}

__device__ __forceinline__ float bf2f(unsigned short u) {
    return __builtin_bit_cast(float, (uint32_t)u << 16);
}

// two bf16 in a u32 -> f32 pair (elem0 = low half, elem1 = high half)
__device__ __forceinline__ f32x2 bfpair(uint32_t w) {
    f32x2 r;
    r.x = __builtin_bit_cast(float, w << 16);
    r.y = __builtin_bit_cast(float, w & 0xffff0000u);
    return r;
}

__device__ __forceinline__ float leaky(float x) {
    return x > 0.0f ? x : NEGS * x;
}

__device__ __forceinline__ void gld_lds16(const unsigned short* g, unsigned short* l) {
    __builtin_amdgcn_global_load_lds(
        (const __attribute__((address_space(1))) void*)g,
        (__attribute__((address_space(3))) void*)l,
        16, 0, 0);
}

// Bijective XCD pair-swizzle for 782 blocks over 8 XCDs (q=97, r=6).
// Makes the two blocks sharing an A-panel (same bx) run on the SAME XCD
// back-to-back -> A read ~once from HBM (r6/r7 FETCH=15MB confirms). Perf-only.
__device__ __forceinline__ void xcd_pair(int orig, int& bx, int& by) {
    int x = orig & 7, g = orig >> 3;
    int v = (x < 6 ? x * 98 : 588 + (x - 6) * 97) + g;
    bx = v >> 1;
    by = v & 1;
}

// ---------------- CSR scan kernels (baseline, unchanged) ----------------

__global__ __launch_bounds__(256) void scanA_kernel(const int* __restrict__ deg,
                                                    int* __restrict__ bsum) {
    __shared__ int ws[4];
    int t = threadIdx.x;
    int idx = blockIdx.x * 256 + t;
    int v = (idx < NNODES) ? deg[idx] : 0;
    int x = v;
    #pragma unroll
    for (int off = 1; off < 64; off <<= 1) x += __shfl_xor(x, off, 64);
    if ((t & 63) == 0) ws[t >> 6] = x;
    __syncthreads();
    if (t == 0) bsum[blockIdx.x] = ws[0] + ws[1] + ws[2] + ws[3];
}

__global__ __launch_bounds__(256) void scanB_kernel(const int* __restrict__ bsum,
                                                    int* __restrict__ boff,
                                                    int* __restrict__ rowptr) {
    __shared__ int s[256];
    int t = threadIdx.x;
    int v = (t < SCAN_BLOCKS) ? bsum[t] : 0;
    s[t] = v;
    __syncthreads();
    #pragma unroll
    for (int off = 1; off < 256; off <<= 1) {
        int y = (t >= off) ? s[t - off] : 0;
        __syncthreads();
        s[t] += y;
        __syncthreads();
    }
    if (t < SCAN_BLOCKS) boff[t] = s[t] - v;  // exclusive
    if (t == 0) rowptr[NNODES] = NEDGES;
}

__global__ __launch_bounds__(256) void scanC_kernel(const int* __restrict__ deg,
                                                    const int* __restrict__ boff,
                                                    int* __restrict__ rowptr,
                                                    int* __restrict__ cursor) {
    __shared__ int ws[4];
    int t = threadIdx.x;
    int lane = t & 63, wv = t >> 6;
    int idx = blockIdx.x * 256 + t;
    int v = (idx < NNODES) ? deg[idx] : 0;
    int x = v;
    #pragma unroll
    for (int off = 1; off < 64; off <<= 1) {
        int y = __shfl_up(x, off, 64);
        if (lane >= off) x += y;
    }
    if (lane == 63) ws[wv] = x;
    __syncthreads();
    int wadd = 0;
    #pragma unroll
    for (int k = 0; k < 4; ++k) if (k < wv) wadd += ws[k];
    int excl = x - v + wadd + boff[blockIdx.x];
    if (idx < NNODES) { rowptr[idx] = excl; cursor[idx] = excl; }
}

// ---------------- combo1: count (atomic) + feats cvt (BW) + weight transpose ----------------

__global__ __launch_bounds__(256) void combo1(const int* __restrict__ dst,
                                              int* __restrict__ deg,
                                              const float* __restrict__ feats,
                                              unsigned short* __restrict__ Abf,
                                              const float* __restrict__ W0,
                                              const float* __restrict__ W1,
                                              const float* __restrict__ W2,
                                              unsigned short* __restrict__ WT) {
    __shared__ float tile[32][33];
    int b = blockIdx.x;
    if (b < COUNT_BLOCKS) {
        int i = b * 256 + threadIdx.x;
        if (i < NEDGES) atomicAdd(&deg[dst[i]], 1);
    } else if (b < COUNT_BLOCKS + CVT_BLOCKS) {
        int i = ((b - COUNT_BLOCKS) * 256 + threadIdx.x) * 4;
        const float4 v = *(const float4*)(feats + i);
        u16x4 o;
        o.x = f2bf(v.x); o.y = f2bf(v.y); o.z = f2bf(v.z); o.w = f2bf(v.w);
        *(u16x4*)(Abf + i) = o;
    } else {
        int t = b - COUNT_BLOCKS - CVT_BLOCKS;  // 0..191
        int bz = t >> 6;
        int bx = t & 7;          // n tile
        int by = (t >> 3) & 7;   // k tile
        const float* W = (bz == 0) ? W0 : (bz == 1) ? W1 : W2;
        unsigned short* T = WT + (size_t)bz * DIM * DIM;
        int tx = threadIdx.x & 31, ty = threadIdx.x >> 5;  // 32 x 8
        #pragma unroll
        for (int j = 0; j < 4; ++j)
            tile[ty + j * 8][tx] = W[(by * 32 + ty + j * 8) * DIM + bx * 32 + tx];
        __syncthreads();
        #pragma unroll
        for (int j = 0; j < 4; ++j)
            T[(bx * 32 + ty + j * 8) * DIM + by * 32 + tx] = f2bf(tile[tx][ty + j * 8]);
    }
}

// ---------------- GEMM body: BK=32 DOUBLE-BUFFERED staging, 32 KB LDS (r10) ----------------
// Next slab's gld_lds issued BEFORE computing the current buffer; one barrier
// per K-step. __launch_bounds__(256,4) keeps regs <= 128/wave -> 4 blocks/CU.

__device__ __forceinline__ void gemm_body(int bx, int by,
        const unsigned short* __restrict__ A, const unsigned short* __restrict__ BT,
        unsigned short* __restrict__ Cb, const float* __restrict__ bias) {
    __shared__ __align__(16) unsigned short As[2][128][32];  // 16 KB
    __shared__ __align__(16) unsigned short Bs[2][128][32];  // 16 KB
    int tid = threadIdx.x;
    int wave = tid >> 6, lane = tid & 63;
    int row0 = bx * 128;
    int col0 = by * 128;
    int wm = (wave >> 1) * 64;
    int wn = (wave & 1) * 64;

    f32x4 acc[4][4] = {};

    int fr = lane & 15;
    int kg = (lane >> 4) * 8;

    #define STAGE32(buf, kt)                                                      \
        do {                                                                      \
            _Pragma("unroll")                                                     \
            for (int r_ = 0; r_ < 2; ++r_) {                                      \
                int idx_ = r_ * 256 + tid;                                        \
                int row_ = idx_ >> 2;                                             \
                int q_ = idx_ & 3;                                                \
                gld_lds16(A + (size_t)(row0 + row_) * DIM + (kt) * 32 + q_ * 8,   \
                          &As[buf][0][0] + idx_ * 8);                             \
                gld_lds16(BT + (size_t)(col0 + row_) * DIM + (kt) * 32 + q_ * 8,  \
                          &Bs[buf][0][0] + idx_ * 8);                             \
            }                                                                     \
        } while (0)

    STAGE32(0, 0);
    __syncthreads();

    int cur = 0;
    #pragma unroll
    for (int kt = 0; kt < 8; ++kt) {
        if (kt < 7) STAGE32(cur ^ 1, kt + 1);
        bf16x8 a_frag[4], b_frag[4];
        #pragma unroll
        for (int i = 0; i < 4; ++i) {
            a_frag[i] = *(const bf16x8*)(&As[cur][wm + i * 16 + fr][kg]);
            b_frag[i] = *(const bf16x8*)(&Bs[cur][wn + i * 16 + fr][kg]);
        }
        #pragma unroll
        for (int i = 0; i < 4; ++i)
            #pragma unroll
            for (int j = 0; j < 4; ++j)
                acc[i][j] = __builtin_amdgcn_mfma_f32_16x16x32_bf16(
                    a_frag[i], b_frag[j], acc[i][j], 0, 0, 0);
        if (kt < 7) { __syncthreads(); cur ^= 1; }
    }
    #undef STAGE32

    int rg = (lane >> 4) * 4;
    #pragma unroll
    for (int i = 0; i < 4; ++i) {
        #pragma unroll
        for (int j = 0; j < 4; ++j) {
            int n = col0 + wn + j * 16 + fr;
            float bv = bias ? bias[n] : 0.0f;
            #pragma unroll
            for (int r = 0; r < 4; ++r) {
                int m = row0 + wm + i * 16 + rg + r;
                Cb[(size_t)m * DIM + n] = f2bf(acc[i][j][r] + bv);
            }
        }
    }
}

__global__ __launch_bounds__(256, 4) void gemm_kernel(const unsigned short* __restrict__ A,
                                                      const unsigned short* __restrict__ BT,
                                                      unsigned short* __restrict__ Cb,
                                                      const float* __restrict__ bias) {
    int bx, by;
    xcd_pair(blockIdx.x, bx, by);
    gemm_body(bx, by, A, BT, Cb, bias);
}

// ---------------- combo2: projection GEMM + CSR fill (independent outputs) ----------------

__global__ __launch_bounds__(256, 4) void combo2(const unsigned short* __restrict__ A,
                                                 const unsigned short* __restrict__ BT,
                                                 unsigned short* __restrict__ Cb,
                                                 const float* __restrict__ bias,
                                                 const int* __restrict__ src,
                                                 const int* __restrict__ dst,
                                                 int* __restrict__ cursor,
                                                 int* __restrict__ csr) {
    int b = blockIdx.x;
    if (b < GEMM_BLOCKS) {
        int bx, by;
        xcd_pair(b, bx, by);
        gemm_body(bx, by, A, BT, Cb, bias);
    } else {
        int i = (b - GEMM_BLOCKS) * 256 + threadIdx.x;
        if (i < NEDGES) {
            int pos = atomicAdd(&cursor[dst[i]], 1);
            csr[pos] = src[i];
        }
    }
}

// ---------------- edge softmax + aggregation: 4 edge-chains/wave ----------------
// r11 counters: VALU 42% / mem 42% -> latency-bound at 2 chains/wave. This
// version: 16-lane quarter per edge (4 chains), each lane covers 16 dims
// (2x16B gathers). u = csr[i] loaded DIRECTLY by all 16 lanes of the quarter
// (same address -> HW broadcast; csr is 2MB, L2-hot) -- no shfl-broadcast in
// the chain (r4's mistake #1) and no predicated body (r4's mistake #2: each
// quarter has its own clean loop bounds).
// Shfl safety: the only in-loop shfl is shfl_xor(du,1) -- partner is the
// adjacent lane in the SAME quarter at the SAME trip count (co-active by
// construction). Cross-quarter reduce (xor 16/32) happens after the loop,
// where all lanes have re-converged. In-wave el/er + packed f32x2 kept (r9/r11).

__global__ __launch_bounds__(256) void agg_kernel(const unsigned short* __restrict__ Hb,
                                                  const float* __restrict__ al,
                                                  const float* __restrict__ ar,
                                                  const int* __restrict__ rowptr,
                                                  const int* __restrict__ csr,
                                                  const float* __restrict__ bias,
                                                  float* __restrict__ outf,
                                                  unsigned short* __restrict__ outb) {
    int wave = threadIdx.x >> 6;
    int lane = threadIdx.x & 63;
    int v = blockIdx.x * 4 + wave;
    if (v >= NNODES) return;
    int q = lane >> 4;       // quarter: which edge of the 4-group
    int s16 = lane & 15;     // lane within quarter
    int c0 = s16 * 16;       // 16 dims per lane (head = s16>>1, 2 lanes/head)

    // attention vectors for this lane's 16 dims, as 8 f32x2 pairs
    f32x2 av[8];
    #pragma unroll
    for (int j = 0; j < 8; ++j) av[j] = *(const f32x2*)(al + c0 + 2 * j);

    // self row (32B = 2 x uint4); derive el_v, er_v (gv dies after this block)
    uint4 hw0 = *(const uint4*)(Hb + (size_t)v * DIM + c0);
    uint4 hw1 = *(const uint4*)(Hb + (size_t)v * DIM + c0 + 8);
    f32x2 hv[8] = { bfpair(hw0.x), bfpair(hw0.y), bfpair(hw0.z), bfpair(hw0.w),
                    bfpair(hw1.x), bfpair(hw1.y), bfpair(hw1.z), bfpair(hw1.w) };
    float el_v, er_v;
    {
        f32x2 dl2 = {0.f, 0.f}, dr2 = {0.f, 0.f};
        #pragma unroll
        for (int j = 0; j < 8; ++j) {
            f32x2 g = *(const f32x2*)(ar + c0 + 2 * j);
            dl2 += hv[j] * av[j];
            dr2 += hv[j] * g;
        }
        float dl = dl2.x + dl2.y;
        float dr = dr2.x + dr2.y;
        dl += __shfl_xor(dl, 1, 64);   // partner: other lane of same head
        dr += __shfl_xor(dr, 1, 64);
        el_v = dl; er_v = dr;
    }

    int beg = rowptr[v], end = rowptr[v + 1];

    float z = 0.0f;
    f32x2 acc2[8] = {};  // acc2[j] = dims (c0+2j, c0+2j+1)

    // self loop on quarter 0 only
    if (q == 0) {
        float ws = __expf(leaky(el_v + er_v));
        z = ws;
        f32x2 w2 = {ws, ws};
        #pragma unroll
        for (int j = 0; j < 8; ++j) acc2[j] = w2 * hv[j];
    }

    #pragma unroll 2
    for (int i = beg + q; i < end; i += 4) {
        int u = csr[i];  // 16 lanes, same address -> broadcast
        const unsigned short* hp = Hb + (size_t)u * DIM + c0;
        uint4 h0 = *(const uint4*)(hp);
        uint4 h1 = *(const uint4*)(hp + 8);
        f32x2 hp0 = bfpair(h0.x), hp1 = bfpair(h0.y), hp2 = bfpair(h0.z), hp3 = bfpair(h0.w);
        f32x2 hp4 = bfpair(h1.x), hp5 = bfpair(h1.y), hp6 = bfpair(h1.z), hp7 = bfpair(h1.w);
        f32x2 d2 = hp0 * av[0] + hp1 * av[1] + hp2 * av[2] + hp3 * av[3]
                 + hp4 * av[4] + hp5 * av[5] + hp6 * av[6] + hp7 * av[7];
        float du = d2.x + d2.y;
        du += __shfl_xor(du, 1, 64);   // same-quarter partner, co-active
        float e = leaky(du + er_v);
        float wi = __expf(e);
        z += wi;
        f32x2 w2 = {wi, wi};
        acc2[0] += w2 * hp0; acc2[1] += w2 * hp1;
        acc2[2] += w2 * hp2; acc2[3] += w2 * hp3;
        acc2[4] += w2 * hp4; acc2[5] += w2 * hp5;
        acc2[6] += w2 * hp6; acc2[7] += w2 * hp7;
    }

    // cross-quarter reduction (all lanes re-converged): 4 copies -> totals
    z += __shfl_xor(z, 16, 64);
    z += __shfl_xor(z, 32, 64);
    #pragma unroll
    for (int j = 0; j < 8; ++j) {
        acc2[j].x += __shfl_xor(acc2[j].x, 16, 64);
        acc2[j].y += __shfl_xor(acc2[j].y, 16, 64);
        acc2[j].x += __shfl_xor(acc2[j].x, 32, 64);
        acc2[j].y += __shfl_xor(acc2[j].y, 32, 64);
    }

    float inv = 1.0f / z;
    // quarter q writes dims [c0 + q*4, c0 + q*4 + 4) -- static acc2 selection
    f32x2 pa, pb;
    if (q == 0)      { pa = acc2[0]; pb = acc2[1]; }
    else if (q == 1) { pa = acc2[2]; pb = acc2[3]; }
    else if (q == 2) { pa = acc2[4]; pb = acc2[5]; }
    else             { pa = acc2[6]; pb = acc2[7]; }
    int o0 = c0 + q * 4;
    float4 b = *(const float4*)(bias + o0);
    float r0 = leaky(pa.x * inv + b.x);
    float r1 = leaky(pa.y * inv + b.y);
    float r2 = leaky(pb.x * inv + b.z);
    float r3 = leaky(pb.y * inv + b.w);
    if (outf) {
        float4 o = { r0, r1, r2, r3 };
        *(float4*)(outf + (size_t)v * DIM + o0) = o;
    } else {
        u16x4 o;
        o.x = f2bf(r0); o.y = f2bf(r1); o.z = f2bf(r2); o.w = f2bf(r3);
        *(u16x4*)(outb + (size_t)v * DIM + o0) = o;
    }
}

// ---------------- launch ----------------

static inline size_t align256(size_t x) { return (x + 255) & ~(size_t)255; }

extern "C" void kernel_launch(void* const* d_in, const int* in_sizes, int n_in,
                              void* d_out, int out_size, void* d_ws, size_t ws_size,
                              hipStream_t stream) {
    const float* feats  = (const float*)d_in[0];
    const int*   src    = (const int*)d_in[1];
    const int*   dst    = (const int*)d_in[2];
    const float* proj_W = (const float*)d_in[3];
    const float* proj_b = (const float*)d_in[4];
    const float* W1     = (const float*)d_in[5];
    const float* al1    = (const float*)d_in[6];
    const float* ar1    = (const float*)d_in[7];
    const float* b1     = (const float*)d_in[8];
    const float* W2     = (const float*)d_in[9];
    const float* al2    = (const float*)d_in[10];
    const float* ar2    = (const float*)d_in[11];
    const float* b2     = (const float*)d_in[12];
    float* out = (float*)d_out;

    uint8_t* w = (uint8_t*)d_ws;
    unsigned short* Abf = (unsigned short*)w; w += align256((size_t)MPAD * DIM * 2);
    unsigned short* Bbf = (unsigned short*)w; w += align256((size_t)MPAD * DIM * 2);
    unsigned short* Hb  = (unsigned short*)w; w += align256((size_t)MPAD * DIM * 2);
    unsigned short* WT  = (unsigned short*)w; w += align256((size_t)3 * DIM * DIM * 2);
    int* deg    = (int*)w;            w += align256((size_t)NNODES * 4);
    int* rowptr = (int*)w;            w += align256((size_t)(NNODES + 1) * 4);
    int* cursor = (int*)w;            w += align256((size_t)NNODES * 4);
    int* csr    = (int*)w;            w += align256((size_t)NEDGES * 4);
    int* bsum   = (int*)w;            w += align256((size_t)SCAN_BLOCKS * 4);
    int* boff   = (int*)w;            w += align256((size_t)SCAN_BLOCKS * 4);

    unsigned short* WT0 = WT;
    unsigned short* WT1 = WT + (size_t)DIM * DIM;
    unsigned short* WT2 = WT + (size_t)2 * DIM * DIM;

    const int node_wave_blocks = (NNODES + 3) / 4;  // one wave per node

    hipMemsetAsync(deg, 0, (size_t)NNODES * 4, stream);

    // count + feats->bf16 + weight transpose, one dispatch
    combo1<<<COUNT_BLOCKS + CVT_BLOCKS + TR_BLOCKS, 256, 0, stream>>>(
        dst, deg, feats, Abf, proj_W, W1, W2, WT);

    scanA_kernel<<<SCAN_BLOCKS, 256, 0, stream>>>(deg, bsum);
    scanB_kernel<<<1, 256, 0, stream>>>(bsum, boff, rowptr);
    scanC_kernel<<<SCAN_BLOCKS, 256, 0, stream>>>(deg, boff, rowptr, cursor);

    // projection gemm + CSR fill, one dispatch
    combo2<<<GEMM_BLOCKS + COUNT_BLOCKS, 256, 0, stream>>>(
        Abf, WT0, Bbf, proj_b, src, dst, cursor, csr);

    // layer 1: Hb = Bbf @ W1 ; agg (in-wave el/er) -> Abf (bf16)
    gemm_kernel<<<GEMM_BLOCKS, 256, 0, stream>>>(Bbf, WT1, Hb, nullptr);
    agg_kernel<<<node_wave_blocks, 256, 0, stream>>>(Hb, al1, ar1, rowptr, csr, b1,
                                                     nullptr, Abf);

    // layer 2: Hb = Abf @ W2 ; agg (in-wave el/er) -> out (fp32)
    gemm_kernel<<<GEMM_BLOCKS, 256, 0, stream>>>(Abf, WT2, Hb, nullptr);
    agg_kernel<<<node_wave_blocks, 256, 0, stream>>>(Hb, al2, ar2, rowptr, csr, b2,
                                                     out, nullptr);
}

// Round 14
// 324.562 us; speedup vs baseline: 1.0009x; 1.0009x over previous
//
#include <hip/hip_runtime.h>
#include <stdint.h>
#include <stddef.h>

#define NNODES 50000
#define NEDGES 500000
#define DIM 256
#define NHEAD 8
#define HDIM 32
#define MPAD 50048   /* 391 * 128 */
#define NEGS 0.2f
#define SCAN_BLOCKS 196    /* ceil(50000/256) */
#define COUNT_BLOCKS 1954  /* ceil(500000/256) */
#define CVT_BLOCKS 12500   /* 50000*256/1024 */
#define TR_BLOCKS 192      /* 8*8*3 */
#define GEMM_BLOCKS 782    /* 391*2 */

typedef __attribute__((ext_vector_type(8))) short bf16x8;
typedef __attribute__((ext_vector_type(4))) float f32x4;
typedef __attribute__((ext_vector_type(2))) float f32x2;
typedef __attribute__((ext_vector_type(4))) unsigned short u16x4;

__device__ __forceinline__ unsigned short f2bf(float f) {
    uint32_t u = __builtin_bit_cast(uint32_t, f);
    uint32_t r = (u + 0x7FFFu + ((u >> 16) & 1u)) >> 16;
    return (unsigned short)r;
}

__device__ __forceinline__ float bf2f(unsigned short u) {
    return __builtin_bit_cast(float, (uint32_t)u << 16);
}

// two bf16 in a u32 -> f32 pair (elem0 = low half, elem1 = high half)
__device__ __forceinline__ f32x2 bfpair(uint32_t w) {
    f32x2 r;
    r.x = __builtin_bit_cast(float, w << 16);
    r.y = __builtin_bit_cast(float, w & 0xffff0000u);
    return r;
}

__device__ __forceinline__ float leaky(float x) {
    return x > 0.0f ? x : NEGS * x;
}

__device__ __forceinline__ void gld_lds16(const unsigned short* g, unsigned short* l) {
    __builtin_amdgcn_global_load_lds(
        (const __attribute__((address_space(1))) void*)g,
        (__attribute__((address_space(3))) void*)l,
        16, 0, 0);
}

// Bijective XCD pair-swizzle for 782 blocks over 8 XCDs (q=97, r=6).
// Makes the two blocks sharing an A-panel (same bx) run on the SAME XCD
// back-to-back -> A read ~once from HBM (r6/r7 FETCH=15MB confirms). Perf-only.
__device__ __forceinline__ void xcd_pair(int orig, int& bx, int& by) {
    int x = orig & 7, g = orig >> 3;
    int v = (x < 6 ? x * 98 : 588 + (x - 6) * 97) + g;
    bx = v >> 1;
    by = v & 1;
}

// ---------------- FUSED scan: one dispatch replaces scanA+scanB+scanC ----------------
// Each block computes its own global offset by cooperatively summing
// deg[0 .. b*256) (strided, block-reduced; deg is 200KB -> L2-resident after
// combo1; worst block reads 49920 ints). Then the proven scanC block-local
// inclusive scan produces rowptr/cursor. No inter-block communication.
// Bound safety: b <= 195 so b*256 <= 49920 < NNODES.

__global__ __launch_bounds__(256) void scan_fused(const int* __restrict__ deg,
                                                  int* __restrict__ rowptr,
                                                  int* __restrict__ cursor) {
    __shared__ int ws[4];
    __shared__ int wp[4];
    int t = threadIdx.x;
    int lane = t & 63, wv = t >> 6;
    int b = blockIdx.x;

    // ---- global offset: sum deg[0 .. b*256) ----
    int pre = 0;
    for (int i = t; i < b * 256; i += 256) pre += deg[i];
    int xs = pre;
    #pragma unroll
    for (int off = 1; off < 64; off <<= 1) xs += __shfl_xor(xs, off, 64);
    if (lane == 0) ws[wv] = xs;
    __syncthreads();
    int base = ws[0] + ws[1] + ws[2] + ws[3];

    // ---- block-local inclusive scan (scanC's proven code) ----
    int idx = b * 256 + t;
    int v = (idx < NNODES) ? deg[idx] : 0;
    int x = v;
    #pragma unroll
    for (int off = 1; off < 64; off <<= 1) {
        int y = __shfl_up(x, off, 64);
        if (lane >= off) x += y;
    }
    if (lane == 63) wp[wv] = x;
    __syncthreads();
    int wadd = 0;
    #pragma unroll
    for (int k = 0; k < 4; ++k) if (k < wv) wadd += wp[k];
    int excl = x - v + wadd + base;
    if (idx < NNODES) { rowptr[idx] = excl; cursor[idx] = excl; }
    if (b == 0 && t == 0) rowptr[NNODES] = NEDGES;
}

// ---------------- combo1: count (atomic) + feats cvt (BW) + weight transpose ----------------

__global__ __launch_bounds__(256) void combo1(const int* __restrict__ dst,
                                              int* __restrict__ deg,
                                              const float* __restrict__ feats,
                                              unsigned short* __restrict__ Abf,
                                              const float* __restrict__ W0,
                                              const float* __restrict__ W1,
                                              const float* __restrict__ W2,
                                              unsigned short* __restrict__ WT) {
    __shared__ float tile[32][33];
    int b = blockIdx.x;
    if (b < COUNT_BLOCKS) {
        int i = b * 256 + threadIdx.x;
        if (i < NEDGES) atomicAdd(&deg[dst[i]], 1);
    } else if (b < COUNT_BLOCKS + CVT_BLOCKS) {
        int i = ((b - COUNT_BLOCKS) * 256 + threadIdx.x) * 4;
        const float4 v = *(const float4*)(feats + i);
        u16x4 o;
        o.x = f2bf(v.x); o.y = f2bf(v.y); o.z = f2bf(v.z); o.w = f2bf(v.w);
        *(u16x4*)(Abf + i) = o;
    } else {
        int t = b - COUNT_BLOCKS - CVT_BLOCKS;  // 0..191
        int bz = t >> 6;
        int bx = t & 7;          // n tile
        int by = (t >> 3) & 7;   // k tile
        const float* W = (bz == 0) ? W0 : (bz == 1) ? W1 : W2;
        unsigned short* T = WT + (size_t)bz * DIM * DIM;
        int tx = threadIdx.x & 31, ty = threadIdx.x >> 5;  // 32 x 8
        #pragma unroll
        for (int j = 0; j < 4; ++j)
            tile[ty + j * 8][tx] = W[(by * 32 + ty + j * 8) * DIM + bx * 32 + tx];
        __syncthreads();
        #pragma unroll
        for (int j = 0; j < 4; ++j)
            T[(bx * 32 + ty + j * 8) * DIM + by * 32 + tx] = f2bf(tile[tx][ty + j * 8]);
    }
}

// ---------------- GEMM body: BK=32 DOUBLE-BUFFERED staging, 32 KB LDS (r10) ----------------
// Next slab's gld_lds issued BEFORE computing the current buffer; one barrier
// per K-step. __launch_bounds__(256,4) keeps regs <= 128/wave -> 4 blocks/CU.

__device__ __forceinline__ void gemm_body(int bx, int by,
        const unsigned short* __restrict__ A, const unsigned short* __restrict__ BT,
        unsigned short* __restrict__ Cb, const float* __restrict__ bias) {
    __shared__ __align__(16) unsigned short As[2][128][32];  // 16 KB
    __shared__ __align__(16) unsigned short Bs[2][128][32];  // 16 KB
    int tid = threadIdx.x;
    int wave = tid >> 6, lane = tid & 63;
    int row0 = bx * 128;
    int col0 = by * 128;
    int wm = (wave >> 1) * 64;
    int wn = (wave & 1) * 64;

    f32x4 acc[4][4] = {};

    int fr = lane & 15;
    int kg = (lane >> 4) * 8;

    #define STAGE32(buf, kt)                                                      \
        do {                                                                      \
            _Pragma("unroll")                                                     \
            for (int r_ = 0; r_ < 2; ++r_) {                                      \
                int idx_ = r_ * 256 + tid;                                        \
                int row_ = idx_ >> 2;                                             \
                int q_ = idx_ & 3;                                                \
                gld_lds16(A + (size_t)(row0 + row_) * DIM + (kt) * 32 + q_ * 8,   \
                          &As[buf][0][0] + idx_ * 8);                             \
                gld_lds16(BT + (size_t)(col0 + row_) * DIM + (kt) * 32 + q_ * 8,  \
                          &Bs[buf][0][0] + idx_ * 8);                             \
            }                                                                     \
        } while (0)

    STAGE32(0, 0);
    __syncthreads();

    int cur = 0;
    #pragma unroll
    for (int kt = 0; kt < 8; ++kt) {
        if (kt < 7) STAGE32(cur ^ 1, kt + 1);
        bf16x8 a_frag[4], b_frag[4];
        #pragma unroll
        for (int i = 0; i < 4; ++i) {
            a_frag[i] = *(const bf16x8*)(&As[cur][wm + i * 16 + fr][kg]);
            b_frag[i] = *(const bf16x8*)(&Bs[cur][wn + i * 16 + fr][kg]);
        }
        #pragma unroll
        for (int i = 0; i < 4; ++i)
            #pragma unroll
            for (int j = 0; j < 4; ++j)
                acc[i][j] = __builtin_amdgcn_mfma_f32_16x16x32_bf16(
                    a_frag[i], b_frag[j], acc[i][j], 0, 0, 0);
        if (kt < 7) { __syncthreads(); cur ^= 1; }
    }
    #undef STAGE32

    int rg = (lane >> 4) * 4;
    #pragma unroll
    for (int i = 0; i < 4; ++i) {
        #pragma unroll
        for (int j = 0; j < 4; ++j) {
            int n = col0 + wn + j * 16 + fr;
            float bv = bias ? bias[n] : 0.0f;
            #pragma unroll
            for (int r = 0; r < 4; ++r) {
                int m = row0 + wm + i * 16 + rg + r;
                Cb[(size_t)m * DIM + n] = f2bf(acc[i][j][r] + bv);
            }
        }
    }
}

__global__ __launch_bounds__(256, 4) void gemm_kernel(const unsigned short* __restrict__ A,
                                                      const unsigned short* __restrict__ BT,
                                                      unsigned short* __restrict__ Cb,
                                                      const float* __restrict__ bias) {
    int bx, by;
    xcd_pair(blockIdx.x, bx, by);
    gemm_body(bx, by, A, BT, Cb, bias);
}

// ---------------- combo2: projection GEMM + CSR fill (independent outputs) ----------------

__global__ __launch_bounds__(256, 4) void combo2(const unsigned short* __restrict__ A,
                                                 const unsigned short* __restrict__ BT,
                                                 unsigned short* __restrict__ Cb,
                                                 const float* __restrict__ bias,
                                                 const int* __restrict__ src,
                                                 const int* __restrict__ dst,
                                                 int* __restrict__ cursor,
                                                 int* __restrict__ csr) {
    int b = blockIdx.x;
    if (b < GEMM_BLOCKS) {
        int bx, by;
        xcd_pair(b, bx, by);
        gemm_body(bx, by, A, BT, Cb, bias);
    } else {
        int i = (b - GEMM_BLOCKS) * 256 + threadIdx.x;
        if (i < NEDGES) {
            int pos = atomicAdd(&cursor[dst[i]], 1);
            csr[pos] = src[i];
        }
    }
}

// ---------------- edge softmax + aggregation (EXACT r11 form — best known) ----------------
// One wave per dst node; 32 lanes per edge, 2 edges per iteration; in-wave
// el/er (8-dim dot + shfl_xor{1,2} over 4-lane head group); packed f32x2 math.
// Structural-optimum note: 4-chain variants measured SLOWER twice --
// r4 (shfl-broadcast in chain): 52.5; r13 (direct load, 16 dims/lane):
// 61.8 us via VGPR 24->40 occupancy drop. Keep this 2-chain low-VGPR form.

__global__ __launch_bounds__(256) void agg_kernel(const unsigned short* __restrict__ Hb,
                                                  const float* __restrict__ al,
                                                  const float* __restrict__ ar,
                                                  const int* __restrict__ rowptr,
                                                  const int* __restrict__ csr,
                                                  const float* __restrict__ bias,
                                                  float* __restrict__ outf,
                                                  unsigned short* __restrict__ outb) {
    int wave = threadIdx.x >> 6;
    int lane = threadIdx.x & 63;
    int v = blockIdx.x * 4 + wave;
    if (v >= NNODES) return;
    int sub = lane & 31;     // lane within half-wave
    int halfe = lane >> 5;   // which edge of the pair this half handles
    int c0 = sub * 8;        // dim offset (8 dims/lane)

    // attention vectors for this lane's 8 dims, as 4 f32x2 pairs
    f32x2 av[4], gv[4];
    #pragma unroll
    for (int j = 0; j < 4; ++j) {
        av[j] = *(const f32x2*)(al + c0 + 2 * j);
        gv[j] = *(const f32x2*)(ar + c0 + 2 * j);
    }

    // self row: both halves load (same cache lines) and derive el_v, er_v
    uint4 hw = *(const uint4*)(Hb + (size_t)v * DIM + c0);
    f32x2 hv[4] = { bfpair(hw.x), bfpair(hw.y), bfpair(hw.z), bfpair(hw.w) };
    f32x2 dl2 = hv[0] * av[0] + hv[1] * av[1] + hv[2] * av[2] + hv[3] * av[3];
    f32x2 dr2 = hv[0] * gv[0] + hv[1] * gv[1] + hv[2] * gv[2] + hv[3] * gv[3];
    float dl = dl2.x + dl2.y;
    float dr = dr2.x + dr2.y;
    dl += __shfl_xor(dl, 1, 64); dl += __shfl_xor(dl, 2, 64);
    dr += __shfl_xor(dr, 1, 64); dr += __shfl_xor(dr, 2, 64);
    float el_v = dl, er_v = dr;

    int beg = rowptr[v], end = rowptr[v + 1];

    float z = 0.0f;
    f32x2 acc2[4] = {};  // acc2[j] = dims (c0+2j, c0+2j+1)

    // self loop on half 0 only
    if (halfe == 0) {
        float ws = __expf(leaky(el_v + er_v));
        z = ws;
        f32x2 w2 = {ws, ws};
        #pragma unroll
        for (int j = 0; j < 4; ++j) acc2[j] = w2 * hv[j];
    }

    #pragma unroll 4
    for (int i = beg + halfe; i < end; i += 2) {
        int u = csr[i];
        uint4 h = *(const uint4*)(Hb + (size_t)u * DIM + c0);
        f32x2 h0 = bfpair(h.x), h1 = bfpair(h.y), h2 = bfpair(h.z), h3 = bfpair(h.w);
        f32x2 d2 = h0 * av[0] + h1 * av[1] + h2 * av[2] + h3 * av[3];
        float du = d2.x + d2.y;
        du += __shfl_xor(du, 1, 64);
        du += __shfl_xor(du, 2, 64);
        float e = leaky(du + er_v);
        float wi = __expf(e);
        z += wi;
        f32x2 w2 = {wi, wi};
        acc2[0] += w2 * h0;
        acc2[1] += w2 * h1;
        acc2[2] += w2 * h2;
        acc2[3] += w2 * h3;
    }

    // cross-half reduction: both halves end with full totals
    z += __shfl_xor(z, 32, 64);
    #pragma unroll
    for (int j = 0; j < 4; ++j) {
        acc2[j].x += __shfl_xor(acc2[j].x, 32, 64);
        acc2[j].y += __shfl_xor(acc2[j].y, 32, 64);
    }

    float inv = 1.0f / z;
    // each half stores 4 of the lane's 8 dims: half0 -> pairs{0,1}, half1 -> pairs{2,3}
    f32x2 pa = (halfe == 0) ? acc2[0] : acc2[2];
    f32x2 pb = (halfe == 0) ? acc2[1] : acc2[3];
    int o0 = c0 + halfe * 4;
    float4 b = *(const float4*)(bias + o0);
    float r0 = leaky(pa.x * inv + b.x);
    float r1 = leaky(pa.y * inv + b.y);
    float r2 = leaky(pb.x * inv + b.z);
    float r3 = leaky(pb.y * inv + b.w);
    if (outf) {
        float4 o = { r0, r1, r2, r3 };
        *(float4*)(outf + (size_t)v * DIM + o0) = o;
    } else {
        u16x4 o;
        o.x = f2bf(r0); o.y = f2bf(r1); o.z = f2bf(r2); o.w = f2bf(r3);
        *(u16x4*)(outb + (size_t)v * DIM + o0) = o;
    }
}

// ---------------- launch ----------------

static inline size_t align256(size_t x) { return (x + 255) & ~(size_t)255; }

extern "C" void kernel_launch(void* const* d_in, const int* in_sizes, int n_in,
                              void* d_out, int out_size, void* d_ws, size_t ws_size,
                              hipStream_t stream) {
    const float* feats  = (const float*)d_in[0];
    const int*   src    = (const int*)d_in[1];
    const int*   dst    = (const int*)d_in[2];
    const float* proj_W = (const float*)d_in[3];
    const float* proj_b = (const float*)d_in[4];
    const float* W1     = (const float*)d_in[5];
    const float* al1    = (const float*)d_in[6];
    const float* ar1    = (const float*)d_in[7];
    const float* b1     = (const float*)d_in[8];
    const float* W2     = (const float*)d_in[9];
    const float* al2    = (const float*)d_in[10];
    const float* ar2    = (const float*)d_in[11];
    const float* b2     = (const float*)d_in[12];
    float* out = (float*)d_out;

    uint8_t* w = (uint8_t*)d_ws;
    unsigned short* Abf = (unsigned short*)w; w += align256((size_t)MPAD * DIM * 2);
    unsigned short* Bbf = (unsigned short*)w; w += align256((size_t)MPAD * DIM * 2);
    unsigned short* Hb  = (unsigned short*)w; w += align256((size_t)MPAD * DIM * 2);
    unsigned short* WT  = (unsigned short*)w; w += align256((size_t)3 * DIM * DIM * 2);
    int* deg    = (int*)w;            w += align256((size_t)NNODES * 4);
    int* rowptr = (int*)w;            w += align256((size_t)(NNODES + 1) * 4);
    int* cursor = (int*)w;            w += align256((size_t)NNODES * 4);
    int* csr    = (int*)w;            w += align256((size_t)NEDGES * 4);

    unsigned short* WT0 = WT;
    unsigned short* WT1 = WT + (size_t)DIM * DIM;
    unsigned short* WT2 = WT + (size_t)2 * DIM * DIM;

    const int node_wave_blocks = (NNODES + 3) / 4;  // one wave per node

    hipMemsetAsync(deg, 0, (size_t)NNODES * 4, stream);

    // count + feats->bf16 + weight transpose, one dispatch
    combo1<<<COUNT_BLOCKS + CVT_BLOCKS + TR_BLOCKS, 256, 0, stream>>>(
        dst, deg, feats, Abf, proj_W, W1, W2, WT);

    // fused 1-dispatch scan (was scanA+scanB+scanC)
    scan_fused<<<SCAN_BLOCKS, 256, 0, stream>>>(deg, rowptr, cursor);

    // projection gemm + CSR fill, one dispatch
    combo2<<<GEMM_BLOCKS + COUNT_BLOCKS, 256, 0, stream>>>(
        Abf, WT0, Bbf, proj_b, src, dst, cursor, csr);

    // layer 1: Hb = Bbf @ W1 ; agg (in-wave el/er) -> Abf (bf16)
    gemm_kernel<<<GEMM_BLOCKS, 256, 0, stream>>>(Bbf, WT1, Hb, nullptr);
    agg_kernel<<<node_wave_blocks, 256, 0, stream>>>(Hb, al1, ar1, rowptr, csr, b1,
                                                     nullptr, Abf);

    // layer 2: Hb = Abf @ W2 ; agg (in-wave el/er) -> out (fp32)
    gemm_kernel<<<GEMM_BLOCKS, 256, 0, stream>>>(Abf, WT2, Hb, nullptr);
    agg_kernel<<<node_wave_blocks, 256, 0, stream>>>(Hb, al2, ar2, rowptr, csr, b2,
                                                     out, nullptr);
}